// Round 2
// baseline (516.325 us; speedup 1.0000x reference)
//
#include <hip/hip_runtime.h>
#include <math.h>

// SimpleRetention bf16 MFMA, round 5b (round 5 + sched-pin hardening):
//  - 256x256 tile, BK=64, 8 waves (512 thr), double-buffered LDS (128 KiB)
//  - raw s_barrier + counted s_waitcnt vmcnt(8): prefetch stays in flight
//    across the barrier (no vmcnt(0) drain in the main loop)
//  - sched_barrier(0) pins prefetch issue BEFORE the counted waitcnt
//  - chunk-XOR swizzled LDS (conflict-free ds_read_b128)
//  - stage 2: strictly-upper att blocks never written (stage 4 never reads them)
//  - stage 4 operand swap (A=att, B=Vt): causal k-limit by row-block, out
//    written in 64B contiguous lane-runs.

typedef __attribute__((ext_vector_type(8))) short short8;
typedef __attribute__((ext_vector_type(4))) float f32x4;
typedef __attribute__((ext_vector_type(4))) unsigned short us4;

#define BM 256
#define BN 256
#define BK 64

static __device__ __forceinline__ unsigned short f2bf(float f) {
    unsigned int u = __float_as_uint(f);
    u += 0x7FFFu + ((u >> 16) & 1u);   // RNE
    return (unsigned short)(u >> 16);
}

static __device__ __forceinline__ void gload16(const unsigned short* g, unsigned short* l) {
    __builtin_amdgcn_global_load_lds(
        (const __attribute__((address_space(1))) unsigned int*)g,
        (__attribute__((address_space(3))) unsigned int*)l, 16, 0, 0);
}

// STAGE: 1 = merged QKV projection (xpos on Q/K, V transposed store)
//        3 = att = (Q K^T)*decay (bf16, lower-tri blocks only)
//        4 = out = att x V  (A=att rows n, B=Vt rows h; causal k-limit by row)
template <int STAGE>
__global__ __launch_bounds__(512, 2)
void gemm_bt(const unsigned short* __restrict__ A,
             const unsigned short* __restrict__ Bt,
             void* __restrict__ Cv,
             unsigned short* __restrict__ Cq,
             unsigned short* __restrict__ Ck,
             unsigned short* __restrict__ Cvt,
             int lda, int ldb, int Kd,
             long long sA, long long sB, long long sC)
{
    constexpr int S = 2048, H = 2048;
    const int rowBase = blockIdx.y * BM;
    const int colBase = blockIdx.x * BN;

    if (STAGE == 3 && blockIdx.x > blockIdx.y) return; // never read by stage 4

    A  += (long long)blockIdx.z * sA;
    Bt += (long long)blockIdx.z * sB;

    __shared__ unsigned short As[2 * BM * BK]; // [buf][256][64], chunks xor-swizzled
    __shared__ unsigned short Bs[2 * BN * BK];

    const int tid  = threadIdx.x;
    const int wave = tid >> 6;
    const int lane = tid & 63;
    const int wm = (wave >> 2) * 128;  // 2 wave-rows x 128
    const int wn = (wave & 3) * 64;    // 4 wave-cols x 64

    f32x4 acc[8][4];
#pragma unroll
    for (int i = 0; i < 8; ++i)
#pragma unroll
        for (int j = 0; j < 4; ++j) acc[i][j] = (f32x4){0.f, 0.f, 0.f, 0.f};

    int kmax = Kd;
    if (STAGE == 4) kmax = rowBase + BM;  // k = m <= n-block end (causal)

    // Staging: wave w covers rows [w*32, w*32+32) of A and B; 4 gload16 each.
    // Lane -> (row = w*32 + g*8 + (lane>>3), dstChunk = lane&7); source chunk
    // xor-swizzled so LDS chunk p of row r holds source chunk p ^ (r&7).
    const int srow = wave * 32 + (lane >> 3);
    const int schunk = ((lane & 7) ^ ((lane >> 3) & 7)) * 8;
    const unsigned short* ga = A  + (size_t)(rowBase + srow) * lda + schunk;
    const unsigned short* gb = Bt + (size_t)(colBase + srow) * ldb + schunk;
    unsigned short* lA0 = As + wave * 2048; // + buf*16384, + g*512 per 8-row group
    unsigned short* lB0 = Bs + wave * 2048;

    const int fr  = lane & 15;
    const int qd  = lane >> 4;       // quad 0..3, k-base = qd*8
    const int fsw = fr & 7;          // xor key per fragment row
    const int nt  = kmax >> 6;

    // prologue: stage tile 0 into buffer 0
#pragma unroll
    for (int g = 0; g < 4; ++g) {
        gload16(ga + (size_t)g * 8 * lda, lA0 + g * 512);
        gload16(gb + (size_t)g * 8 * ldb, lB0 + g * 512);
    }

    for (int t = 0; t < nt; ++t) {
        const int b = t & 1;
        if (t + 1 < nt) {
            // issue next tile into the other buffer (its readers finished
            // before the previous trailing barrier), then wait only for THIS
            // tile's 8 loads: vmcnt(8) leaves the 8 just issued in flight.
            const unsigned short* gA = ga + (t + 1) * BK;
            const unsigned short* gB = gb + (t + 1) * BK;
            unsigned short* lA = lA0 + (b ^ 1) * 16384;
            unsigned short* lB = lB0 + (b ^ 1) * 16384;
#pragma unroll
            for (int g = 0; g < 4; ++g) {
                gload16(gA + (size_t)g * 8 * lda, lA + g * 512);
                gload16(gB + (size_t)g * 8 * ldb, lB + g * 512);
            }
            __builtin_amdgcn_sched_barrier(0);   // pin loads BEFORE the count
            asm volatile("s_waitcnt vmcnt(8)" ::: "memory");
        } else {
            __builtin_amdgcn_sched_barrier(0);
            asm volatile("s_waitcnt vmcnt(0)" ::: "memory");
        }
        __builtin_amdgcn_sched_barrier(0);
        __builtin_amdgcn_s_barrier();          // all waves' tile-t loads landed
        asm volatile("" ::: "memory");

        const unsigned short* Ab = As + b * 16384;
        const unsigned short* Bb = Bs + b * 16384;
#pragma unroll
        for (int kk = 0; kk < 2; ++kk) {
            short8 bfr[4], afr[8];
#pragma unroll
            for (int j = 0; j < 4; ++j) {
                int row = wn + j * 16 + fr;
                bfr[j] = *(const short8*)&Bb[row * 64 + (((kk * 4 + qd) ^ fsw) * 8)];
            }
#pragma unroll
            for (int i = 0; i < 8; ++i) {
                int row = wm + i * 16 + fr;
                afr[i] = *(const short8*)&Ab[row * 64 + (((kk * 4 + qd) ^ fsw) * 8)];
            }
#pragma unroll
            for (int i = 0; i < 8; ++i)
#pragma unroll
                for (int j = 0; j < 4; ++j)
                    acc[i][j] = __builtin_amdgcn_mfma_f32_16x16x32_bf16(afr[i], bfr[j], acc[i][j], 0, 0, 0);
        }
        asm volatile("" ::: "memory");
        __builtin_amdgcn_s_barrier();          // reads of buf b done before overwrite
    }

    // C/D layout: col = lane&15, row = (lane>>4)*4 + reg
    if (STAGE == 1) {
        const int mode = colBase >> 11; // 0=Q, 1=K, 2=V
        if (mode < 2) {
            unsigned short* Co = (mode == 0) ? Cq : Ck;
            const float psgn = (mode == 1) ? -1.953125e-3f : 1.953125e-3f; // ±1/512
#pragma unroll
            for (int j = 0; j < 4; ++j) {
                int gc = (colBase & 2047) + wn + j * 16 + fr;
                float c0 = (float)(gc & ~1);
                float l2sv = log2f((c0 + 819.2f) * (1.0f / 2867.2f)) * psgn;
                float invf = exp2f(c0 * -0.0064881407f); // 10000^(-c0/2048)
                float s1, c1;
                sincosf(invf, &s1, &c1);
#pragma unroll
                for (int i = 0; i < 8; ++i) {
                    int gr0 = rowBase + wm + i * 16 + qd * 4;
                    float fn = (float)(gr0 & (S - 1));
                    float sN, cN;
                    sincosf(fn * invf, &sN, &cN);
#pragma unroll
                    for (int r = 0; r < 4; ++r) {
                        float scale = exp2f(fn * l2sv);
                        float cs = cN * scale, ss = sN * scale;
                        float v = acc[i][j][r];
                        float o = __shfl_xor(v, 1);
                        float res = (gc & 1) ? fmaf(v, cs, o * ss) : fmaf(v, cs, -o * ss);
                        Co[(size_t)(gr0 + r) * H + gc] = f2bf(res);
                        float sn2 = sN * c1 + cN * s1; // rotate by invf
                        cN = cN * c1 - sN * s1;
                        sN = sn2;
                        fn += 1.0f;
                    }
                }
            }
        } else { // V: store transposed Vt[h][8192]
#pragma unroll
            for (int j = 0; j < 4; ++j) {
                int gh = (colBase & 2047) + wn + j * 16 + fr;
#pragma unroll
                for (int i = 0; i < 8; ++i) {
                    int gm0 = rowBase + wm + i * 16 + qd * 4;
                    us4 p;
#pragma unroll
                    for (int r = 0; r < 4; ++r) p[r] = f2bf(acc[i][j][r]);
                    *(us4*)&Cvt[(size_t)gh * 8192 + gm0] = p;
                }
            }
        }
    } else if (STAGE == 3) {
        unsigned short* att = (unsigned short*)Cv + (long long)blockIdx.z * sC;
#pragma unroll
        for (int j = 0; j < 4; ++j) {
            int m = colBase + wn + j * 16 + fr;
#pragma unroll
            for (int i = 0; i < 8; ++i) {
                int n0 = rowBase + wm + i * 16 + qd * 4;
#pragma unroll
                for (int r = 0; r < 4; ++r) {
                    int d = n0 + r - m;
                    float v = (d >= 0) ? acc[i][j][r] * exp2f((float)d * -0.045803598f) : 0.0f;
                    att[(size_t)(n0 + r) * S + m] = f2bf(v);
                }
            }
        }
    } else { // STAGE 4: C rows = n, cols = h -> out[n][h], 64B lane-runs
        float* Co = (float*)Cv + (long long)blockIdx.z * sC;
#pragma unroll
        for (int j = 0; j < 4; ++j) {
            int gh = colBase + wn + j * 16 + fr;
#pragma unroll
            for (int i = 0; i < 8; ++i) {
                int gn0 = rowBase + wm + i * 16 + qd * 4;
#pragma unroll
                for (int r = 0; r < 4; ++r)
                    Co[(size_t)(gn0 + r) * H + gh] = acc[i][j][r];
            }
        }
    }
}

__global__ __launch_bounds__(256)
void cvt_f32_bf16(const float* __restrict__ x, unsigned short* __restrict__ y) {
    int i = blockIdx.x * 256 + threadIdx.x;
    float4 v = ((const float4*)x)[i];
    us4 o = {f2bf(v.x), f2bf(v.y), f2bf(v.z), f2bf(v.w)};
    ((us4*)y)[i] = o;
}

// three W [2048][2048] fp32 -> WtAll [6144][2048] bf16 (transposed per chunk)
__global__ __launch_bounds__(256)
void cvt_transpose3(const float* __restrict__ W0, const float* __restrict__ W1,
                    const float* __restrict__ W2, unsigned short* __restrict__ Wt) {
    __shared__ float t[64][65];
    const float* W = (blockIdx.z == 0) ? W0 : (blockIdx.z == 1) ? W1 : W2;
    unsigned short* Wo = Wt + (size_t)blockIdx.z * 4194304;
    int bx = blockIdx.x * 64, by = blockIdx.y * 64;
    int tx = threadIdx.x & 63, ty = threadIdx.x >> 6;
#pragma unroll
    for (int r = 0; r < 64; r += 4)
        t[ty + r][tx] = W[(size_t)(by + ty + r) * 2048 + bx + tx];
    __syncthreads();
#pragma unroll
    for (int r = 0; r < 64; r += 4)
        Wo[(size_t)(bx + ty + r) * 2048 + by + tx] = f2bf(t[tx][ty + r]);
}

extern "C" void kernel_launch(void* const* d_in, const int* in_sizes, int n_in,
                              void* d_out, int out_size, void* d_ws, size_t ws_size,
                              hipStream_t stream) {
    const int S = 2048, H = 2048;
    const long long MH = 16777216;         // 8192*2048 elements
    const long long HH = 4194304;          // 2048*2048
    const long long SH = (long long)S * H; // per-batch stride
    const long long SS = (long long)S * S;

    const float* X  = (const float*)d_in[0];
    const float* WQ = (const float*)d_in[1];
    const float* WK = (const float*)d_in[2];
    const float* WV = (const float*)d_in[3];
    float* out = (float*)d_out;

    unsigned short* Xb    = (unsigned short*)d_ws;
    unsigned short* WtAll = Xb + MH;        // [6144][2048]
    unsigned short* Qb    = WtAll + 3 * HH;
    unsigned short* Kb    = Qb + MH;
    unsigned short* Vt    = Kb + MH;        // [2048][8192]
    unsigned short* att   = Vt + MH;        // [4][2048][2048]

    cvt_f32_bf16<<<16384, 256, 0, stream>>>(X, Xb);
    cvt_transpose3<<<dim3(32, 32, 3), 256, 0, stream>>>(WQ, WK, WV, WtAll);

    // stage 1: merged QKV projection, M=8192, N=6144
    gemm_bt<1><<<dim3(24, 32), 512, 0, stream>>>(Xb, WtAll, nullptr, Qb, Kb, Vt,
                                                 H, H, H, 0, 0, 0);
    // stage 2: att = (Q K^T) * decay, lower-tri blocks only
    gemm_bt<3><<<dim3(8, 8, 4), 512, 0, stream>>>(Qb, Kb, att, nullptr, nullptr, nullptr,
                                                  H, H, H, SH, SH, SS);
    // stage 3: out = att x V (A=att lda=S; B=Vt ldb=8192, batch col offset 2048)
    gemm_bt<4><<<dim3(8, 8, 4), 512, 0, stream>>>(att, Vt, out, nullptr, nullptr, nullptr,
                                                  S, 8192, S, SS, 2048, SH);
}